// Round 7
// baseline (2432.115 us; speedup 1.0000x reference)
//
#include <hip/hip_runtime.h>
#include <cstdint>
#include <cstddef>

typedef unsigned short ubf;   // bf16 bit pattern (internal use only)
typedef unsigned int   u32;
typedef __attribute__((ext_vector_type(8))) short short8;
typedef __attribute__((ext_vector_type(4))) float f32x4;
typedef __attribute__((ext_vector_type(4))) float f4v;
typedef __attribute__((ext_vector_type(2))) float f2v;
typedef __attribute__((ext_vector_type(4))) unsigned short us4;

#define NEG_INF_F (-1000000000.0f)
#define FOURH 2048

// d_out element offsets in FLOAT32 elements (confirmed r8/r9).
#define ENC_SEG   8388608            // 64*256*512
#define REC_OFF   25165824
#define REC_SEG   8192000            // 64*256*500
#define MASK_OFF  49741824
#define LOGB_OFF  49774592
#define SAMB_OFF  49807360
#define LOGZ_OFF  49856512
#define SAMZ_OFF  49881088

// scratch inside recs[2] dead region (f32 elements from region base).
// r17 replay-safety audit (tail_kernel seg2 bcast=1 overwrites ALL of recs[2]):
//   P      — rewritten by gemm_P before lstm(0) reads          [next replay]
//   hbuf   — gated by flags; flags re-zeroed by init_kernel    [next replay]
//   maskf  — rewritten by softmax(0) before lstm(1) reads
//   logcum — rewritten (seg==0 path) before first read
//   partf  — rewritten by gemm_b before softmax reads
//   encb   — rewritten by lstm(0) before gemm_b(0) reads
#define SCR_P       0               // bf16[512][2048] = 524,288 f32
#define SCR_HBUF    524288          // bf16[2][4][16][512] = 32,768 f32
#define SCR_FLAGS   557056          // 1,024 f32 (64 flags x 16-dword padding)
#define SCR_MASKF   558080          // 16,384 f32
#define SCR_LOGCUM  574464          // 16,384 f32
#define SCR_PART    590848          // 131,072 f32
#define SCR_ENCB    1048576         // bf16[16384][512] = 4,194,304 f32

__device__ __forceinline__ float bf2f(ubf u){
  union { u32 i; float f; } v; v.i = ((u32)u) << 16; return v.f;
}
__device__ __forceinline__ ubf f2bf(float f){
  union { float f; u32 i; } v; v.f = f;
  u32 x = v.i;
  u32 r = (x + 0x7FFFu + ((x >> 16) & 1u)) >> 16;   // RNE
  return (ubf)r;
}
__device__ __forceinline__ float sigm(float x){
  return 1.0f / (1.0f + __expf(-x));
}
__device__ __forceinline__ float tanh_fast(float x){
  x = fminf(fmaxf(x, -20.0f), 20.0f);
  float e2 = __expf(2.0f * x);
  return (e2 - 1.0f) / (e2 + 1.0f);
}

// ---------------------------------------------------------------- init flags
__global__ void init_kernel(u32* flags){
  int tid = threadIdx.x;
  #pragma unroll
  for (int i = 0; i < 4; i++) flags[tid + i*256] = 0u;
}

// ---------------------------------------------------------------- GEMM (MFMA 16x16x32 bf16)
__global__ __launch_bounds__(256, 2) void gemm_kernel(
    const void* __restrict__ Aptr, int a_f32,
    const float* __restrict__ Bf, const float* __restrict__ bias,
    ubf* __restrict__ C, const float* __restrict__ wb2, float* __restrict__ part,
    int M, int N, int K, int relu, int mclamp)
{
  __shared__ __align__(16) ubf As[128*40];   // [128 rows][32 k + 8 pad]
  __shared__ __align__(16) ubf Bs[128*40];   // transposed: [128 n][32 k + 8 pad]
  int tid  = threadIdx.x;
  int bn   = blockIdx.x, bm = blockIdx.y;
  int w    = tid >> 6, lane = tid & 63, quad = lane >> 4, l16 = lane & 15;
  int wm   = w >> 1, wn = w & 1;

  f32x4 acc[4][4];
  #pragma unroll
  for (int i = 0; i < 4; i++)
    #pragma unroll
    for (int j = 0; j < 4; j++)
      #pragma unroll
      for (int r = 0; r < 4; r++) acc[i][j][r] = 0.0f;

  for (int k0 = 0; k0 < K; k0 += 32) {
    if (a_f32){
      const float* Af = (const float*)Aptr;
      #pragma unroll
      for (int h = 0; h < 4; h++){
        int v   = tid + h*256;          // 0..1023 float4 units
        int row = v >> 3, kc = (v & 7) * 4;
        int rm  = bm*128 + row;
        int ar  = rm < mclamp ? rm : mclamp;
        f4v q = *(const f4v*)(Af + (size_t)ar * K + k0 + kc);
        us4 s; s[0]=f2bf(q[0]); s[1]=f2bf(q[1]); s[2]=f2bf(q[2]); s[3]=f2bf(q[3]);
        *(us4*)&As[row*40 + kc] = s;
      }
    } else {
      const ubf* Ab = (const ubf*)Aptr;
      #pragma unroll
      for (int h = 0; h < 2; h++){
        int v   = tid + h*256;          // 0..511 vec8 units
        int row = v >> 2, kc = (v & 3) * 8;
        int rm  = bm*128 + row;
        int ar  = rm < mclamp ? rm : mclamp;
        uint4 q = *(const uint4*)(Ab + (size_t)ar * K + k0 + kc);
        *(uint4*)&As[row*40 + kc] = q;
      }
    }
    #pragma unroll
    for (int h = 0; h < 4; h++){
      int v  = tid + h*256;             // 0..1023 float4 units
      int kk = v >> 5, nn = (v & 31) * 4;
      f4v q = *(const f4v*)(Bf + (size_t)(k0 + kk) * N + bn*128 + nn);
      #pragma unroll
      for (int j = 0; j < 4; j++) Bs[(nn + j)*40 + kk] = f2bf(q[j]);
    }
    __syncthreads();
    short8 af[4], bfr[4];
    #pragma unroll
    for (int i = 0; i < 4; i++){
      int row = wm*64 + i*16 + l16;
      af[i]  = *(const short8*)&As[row*40 + quad*8];
      int col = wn*64 + i*16 + l16;
      bfr[i] = *(const short8*)&Bs[col*40 + quad*8];
    }
    #pragma unroll
    for (int i = 0; i < 4; i++)
      #pragma unroll
      for (int j = 0; j < 4; j++)
        acc[i][j] = __builtin_amdgcn_mfma_f32_16x16x32_bf16(af[i], bfr[j], acc[i][j], 0, 0, 0);
    __syncthreads();
  }
  if (!wb2){
    #pragma unroll
    for (int i = 0; i < 4; i++){
      #pragma unroll
      for (int j = 0; j < 4; j++){
        int n   = bn*128 + wn*64 + j*16 + l16;
        float bv = bias ? bias[n] : 0.0f;
        #pragma unroll
        for (int r = 0; r < 4; r++){
          int m   = bm*128 + wm*64 + i*16 + quad*4 + r;
          float vv = acc[i][j][r] + bv;
          if (relu) vv = fmaxf(vv, 0.0f);
          C[(size_t)m * N + n] = f2bf(vv);
        }
      }
    }
  } else {
    #pragma unroll
    for (int i = 0; i < 4; i++){
      f32x4 rp;
      #pragma unroll
      for (int r = 0; r < 4; r++) rp[r] = 0.0f;
      #pragma unroll
      for (int j = 0; j < 4; j++){
        int n   = bn*128 + wn*64 + j*16 + l16;
        float bv = bias[n];
        float wv = wb2[n];
        #pragma unroll
        for (int r = 0; r < 4; r++)
          rp[r] += fmaxf(acc[i][j][r] + bv, 0.0f) * wv;
      }
      #pragma unroll
      for (int off = 1; off < 16; off <<= 1)
        #pragma unroll
        for (int r = 0; r < 4; r++)
          rp[r] += __shfl_xor(rp[r], off, 64);
      if (l16 == 0){
        #pragma unroll
        for (int r = 0; r < 4; r++){
          int m = bm*128 + wm*64 + i*16 + quad*4 + r;
          part[(size_t)(bn*2 + wn)*16384 + m] = rp[r];
        }
      }
    }
  }
}

// ---------------------------------------------------------------- fused per-batch tail:
// readout (r in LDS) -> z-head -> reparam -> decoder -> broadcast to all 256 rows.
// One block per batch, 256 threads. All inputs complete before launch; writes
// only this batch's rec rows + lz/sz outputs — race-free without any cross-block
// sync. Math identical to the proven r12 readout (sequential t) + r12 zdec.
__device__ void tail_block(int b,
    const float* __restrict__ enc,    // [64][256][512] f32 (seg's enc)
    const float* __restrict__ sb_g,   // [64][256] f32 (seg's sample_b, FINAL out region)
    const float* __restrict__ Wz1, const float* __restrict__ bz1,
    const float* __restrict__ Wz2, const float* __restrict__ bz2,
    const float* __restrict__ epsz,   // seg's eps slice
    const float* __restrict__ Wd1, const float* __restrict__ bd1,
    const float* __restrict__ Wd2, const float* __restrict__ bd2,
    float* __restrict__ lzout, float* __restrict__ szout,
    float* __restrict__ recseg)
{
  __shared__ float sb[256];
  __shared__ float r[512];
  __shared__ float hz[512];
  __shared__ float lz[128];
  __shared__ float sz[64];
  __shared__ float hd[512];
  int tid = threadIdx.x;
  sb[tid] = sb_g[b*256 + tid];
  __syncthreads();
  // readout = sum_{t=0}^{254} enc[b,t,:] * sb[b,t+1]
  {
    const float* base = enc + ((size_t)b*256)*512 + tid*2;
    float a0 = 0.0f, a1 = 0.0f;
    for (int t = 0; t < 255; t++){
      float m = sb[t + 1];
      f2v q = *(const f2v*)(base + (size_t)t*512);
      a0 += m * q[0];
      a1 += m * q[1];
    }
    r[tid*2]     = a0;
    r[tid*2 + 1] = a1;
  }
  __syncthreads();
  {
    float a0 = bz1[tid], a1 = bz1[tid + 256];
    for (int i = 0; i < 512; i++){
      float ri = r[i];
      a0 += ri * Wz1[(size_t)i*512 + tid];
      a1 += ri * Wz1[(size_t)i*512 + tid + 256];
    }
    hz[tid]       = fmaxf(a0, 0.0f);
    hz[tid + 256] = fmaxf(a1, 0.0f);
  }
  __syncthreads();
  if (tid < 128){
    float a = bz2[tid];
    for (int i = 0; i < 512; i++) a += hz[i] * Wz2[(size_t)i*128 + tid];
    lz[tid] = a;
    lzout[b*128 + tid] = a;
  }
  __syncthreads();
  if (tid < 64){
    float mu = lz[tid], lv = lz[64 + tid];
    float v = mu + __expf(0.5f * lv) * epsz[b*64 + tid];
    sz[tid] = v;
    szout[b*64 + tid] = v;
  }
  __syncthreads();
  {
    float a0 = bd1[tid], a1 = bd1[tid + 256];
    for (int l = 0; l < 64; l++){
      float s = sz[l];
      a0 += s * Wd1[l*512 + tid];
      a1 += s * Wd1[l*512 + tid + 256];
    }
    hd[tid]       = fmaxf(a0, 0.0f);
    hd[tid + 256] = fmaxf(a1, 0.0f);
  }
  __syncthreads();
  {
    float a0 = bd2[tid];
    float a1 = (tid < 244) ? bd2[tid + 256] : 0.0f;
    for (int h = 0; h < 512; h++){
      float hh = hd[h];
      a0 += hh * Wd2[(size_t)h*500 + tid];
      if (tid < 244) a1 += hh * Wd2[(size_t)h*500 + tid + 256];
    }
    for (int t = 0; t < 256; t++){
      float* row = recseg + (size_t)b*128000 + (size_t)t*500;
      row[tid] = a0;
      if (tid < 244) row[tid + 256] = a1;
    }
  }
}

// ---------------------------------------------------------------- persistent masked-LSTM
// r17 = r12/r15/r16 protocol byte-identical (608-615us across 3 runs; best of
// 5 protocols tried). New: blocks 64..127 (segs 1,2 only) run the PREVIOUS
// segment's tail (readout+zdec+broadcast) on otherwise-idle CUs — fully hidden
// under the 614us lstm. Tail blocks never touch the lstm protocol state.
__global__ __launch_bounds__(256, 1) void lstm_kernel(
    const ubf* __restrict__ Pt,      // [512(V pad)][4H] bf16, includes b_lstm
    const int* __restrict__ actions, // [B][T]
    const float* __restrict__ Whf,   // [H][4H] f32
    const float* __restrict__ mask,  // [B][T] f32 or null (seg 0)
    float* __restrict__ enc,         // d_out + seg*ENC_SEG (f32)
    ubf* __restrict__ encb,          // scratch bf16 enc copy or null (seg 2)
    ubf* hbuf,                       // scratch: [2][4][16][512] bf16
    u32* flags,                      // scratch: [64]x16-dword-padded
    int seg,
    // ---- fused tail (previous segment) args; used by blocks >= 64 ----
    const float* __restrict__ tenc, const float* __restrict__ tsb,
    const float* __restrict__ teps,
    const float* __restrict__ Wz1, const float* __restrict__ bz1,
    const float* __restrict__ Wz2, const float* __restrict__ bz2,
    const float* __restrict__ Wd1, const float* __restrict__ bd1,
    const float* __restrict__ Wd2, const float* __restrict__ bd2,
    float* __restrict__ tlz, float* __restrict__ tsz, float* __restrict__ trec)
{
  if (blockIdx.x >= 64){
    tail_block(blockIdx.x - 64, tenc, tsb, Wz1, bz1, Wz2, bz2, teps,
               Wd1, bd1, Wd2, bd2, tlz, tsz, trec);
    return;
  }
  __shared__ __align__(16) ubf   htile[16*520];   // [16 b][512 + 8 pad]
  __shared__ __align__(16) ubf   ptile[16*136];   // [16 b][128 + 8 pad]
  __shared__ __align__(16) float ztile[16*132];   // [16 b][128 + 4 pad]

  int tid  = threadIdx.x;
  int wv   = tid >> 6;            // wave = gate index 0..3 (i,f,g,o)
  int lane = tid & 63, quad = lane >> 4, l16 = lane & 15;
  int bg   = blockIdx.x >> 4, cg = blockIdx.x & 15;
  int j0   = cg * 32;             // unit base

  // persistent Wh B-fragments: B[k][n], n = lane&15, k = quad*8+j
  short8 bfrag[2][16];
  #pragma unroll
  for (int h = 0; h < 2; h++){
    int col = wv*512 + j0 + h*16 + l16;
    #pragma unroll
    for (int kt = 0; kt < 16; kt++){
      short8 t8;
      #pragma unroll
      for (int j = 0; j < 8; j++){
        int k = kt*32 + quad*8 + j;
        t8[j] = (short)f2bf(Whf[(size_t)k * FOURH + col]);
      }
      bfrag[h][kt] = t8;
    }
  }

  float cst0 = 0.0f, cst1 = 0.0f;      // c-state for this thread's 2 (batch,unit) pairs
  int bl = tid >> 4;                   // local batch 0..15
  int up = (tid & 15) * 2;             // unit pair base within 32
  int bglob = bg*16 + bl;
  u32* htile32 = (u32*)htile;
  unsigned epoch0 = (unsigned)seg * 256u;
  u32* myflag = &flags[(bg*16 + (tid >> 4))*16];   // producer block this thread reads

  for (int t = 0; t < 256; ++t){
    // stage P tile [16 b][4 gates x 32 units], gathered by action id (L2-resident);
    // issued first so its latency hides under the flag poll below.
    {
      int act  = actions[(size_t)bglob * 256 + t];
      int colc = (tid & 15) * 8;
      int gate = colc >> 5, cw = colc & 31;
      uint4 q = *(const uint4*)(Pt + (size_t)act * FOURH + gate*512 + j0 + cw);
      *(uint4*)&ptile[bl*136 + colc] = q;
    }
    if (t > 0){
      // each thread polls the ONE producer flag it depends on, then loads its
      // 16 words (word index tid of 16 rows, all from block cg'=tid>>4).
      unsigned tgt = epoch0 + (unsigned)t;
      while (__hip_atomic_load(myflag, __ATOMIC_RELAXED, __HIP_MEMORY_SCOPE_AGENT) < tgt)
        __builtin_amdgcn_s_sleep(1);
      const u32* src = (const u32*)(hbuf + (size_t)(((t+1)&1)*4 + bg) * 16 * 512);
      u32 tmp[16];
      #pragma unroll
      for (int i = 0; i < 16; i++)
        tmp[i] = __hip_atomic_load(&src[tid + 256*i], __ATOMIC_RELAXED, __HIP_MEMORY_SCOPE_AGENT);
      #pragma unroll
      for (int i = 0; i < 16; i++)
        htile32[i*260 + tid] = tmp[i];     // row i = batch, 260 u32/row (padded)
    }
    __syncthreads();   // sync A: htile (and ptile) staged for this step

    f32x4 a0, a1;
    #pragma unroll
    for (int r = 0; r < 4; r++){ a0[r] = 0.0f; a1[r] = 0.0f; }
    if (t > 0){
      #pragma unroll
      for (int kt = 0; kt < 16; kt++){
        short8 af = *(const short8*)&htile[l16*520 + kt*32 + quad*8];
        a0 = __builtin_amdgcn_mfma_f32_16x16x32_bf16(af, bfrag[0][kt], a0, 0, 0, 0);
        a1 = __builtin_amdgcn_mfma_f32_16x16x32_bf16(af, bfrag[1][kt], a1, 0, 0, 0);
      }
    }
    // redistribute z via LDS so each thread gets matching i,f,g,o
    #pragma unroll
    for (int r = 0; r < 4; r++){
      ztile[(quad*4 + r)*132 + wv*32 + l16]      = a0[r];
      ztile[(quad*4 + r)*132 + wv*32 + 16 + l16] = a1[r];
    }
    __syncthreads();   // sync B: ztile ready for elementwise

    float m = mask ? mask[(size_t)bglob * 256 + t] : 1.0f;
    f2v ev;
    ubf hp[2];
    #pragma unroll
    for (int p = 0; p < 2; p++){
      int u = up + p;
      float zi = ztile[bl*132 +       u] + bf2f(ptile[bl*136 +       u]);
      float zf = ztile[bl*132 + 32 + u] + bf2f(ptile[bl*136 + 32 + u]);
      float zg = ztile[bl*132 + 64 + u] + bf2f(ptile[bl*136 + 64 + u]);
      float zo = ztile[bl*132 + 96 + u] + bf2f(ptile[bl*136 + 96 + u]);
      float is = sigm(zi), fs = sigm(zf), gt = tanh_fast(zg), os = sigm(zo);
      float cp = p ? cst1 : cst0;
      float cn = fs * cp + is * gt;
      float hn = os * tanh_fast(cn);
      ev[p] = hn;                       // enc records PRE-mask h (f32)
      float cm = m * cn;
      if (p) cst1 = cm; else cst0 = cm;
      hp[p] = f2bf(m * hn);             // masked h carried forward (bf16)
    }
    {
      u32 hword = (u32)hp[0] | ((u32)hp[1] << 16);
      u32* dst = (u32*)(hbuf + (size_t)((t&1)*4 + bg) * 16 * 512);
      __hip_atomic_store(&dst[(bl*512 + j0 + up) >> 1], hword,
                         __ATOMIC_RELAXED, __HIP_MEMORY_SCOPE_AGENT);
    }
    __threadfence_block();   // ordering intent only (block scope: no cache ops)
    __syncthreads();         // drain: vmcnt(0) -> sc1 h-stores committed at L3
    if (tid == 0)
      __hip_atomic_store(&flags[(bg*16 + cg)*16], epoch0 + (unsigned)t + 1u,
                         __ATOMIC_RELAXED, __HIP_MEMORY_SCOPE_AGENT);
    // enc stores AFTER the announce: HBM acks off the protocol path; they
    // drain during the next step's poll window (covered by next drain).
    *(f2v*)(enc + ((size_t)bglob * 256 + t) * 512 + j0 + up) = ev;
    if (encb){
      u32 ebw = (u32)f2bf(ev[0]) | ((u32)f2bf(ev[1]) << 16);
      *(u32*)&encb[((size_t)bglob * 256 + t) * 512 + j0 + up] = ebw;
    }
  }
}

// ---------------------------------------------------------------- standalone tail (seg 2)
__global__ __launch_bounds__(256, 4) void tail_kernel(
    const float* __restrict__ enc, const float* __restrict__ sb_g,
    const float* __restrict__ Wz1, const float* __restrict__ bz1,
    const float* __restrict__ Wz2, const float* __restrict__ bz2,
    const float* __restrict__ epsz,
    const float* __restrict__ Wd1, const float* __restrict__ bd1,
    const float* __restrict__ Wd2, const float* __restrict__ bd2,
    float* __restrict__ lzout, float* __restrict__ szout, float* __restrict__ recseg)
{
  tail_block(blockIdx.x, enc, sb_g, Wz1, bz1, Wz2, bz2, epsz,
             Wd1, bd1, Wd2, bd2, lzout, szout, recseg);
}

// ---------------------------------------------------------------- softmax + cumsum + mask update (per batch)
__global__ __launch_bounds__(256, 4) void softmax_kernel(
    const float* __restrict__ part, const float* __restrict__ bb2, const float* __restrict__ gum,
    float* __restrict__ lout,
    float* __restrict__ sbout,
    float* __restrict__ logcum, float* __restrict__ maskf, float* __restrict__ maskout,
    int seg)
{
  __shared__ float red[256];
  __shared__ float cs[256];
  int b = blockIdx.x, t = threadIdx.x;
  float raw = 0.0f;
  #pragma unroll
  for (int s = 0; s < 8; s++) raw += part[s*16384 + b*256 + t];
  float lg  = (t == 0) ? NEG_INF_F : (raw + bb2[0]);
  lout[b*256 + t] = lg;
  float x = lg + gum[b*256 + t];   // TEMP_B = 1
  red[t] = x; __syncthreads();
  for (int o = 128; o > 0; o >>= 1){ if (t < o) red[t] = fmaxf(red[t], red[t+o]); __syncthreads(); }
  float mx = red[0]; __syncthreads();
  float e = __expf(x - mx);
  red[t] = e; __syncthreads();
  for (int o = 128; o > 0; o >>= 1){ if (t < o) red[t] += red[t+o]; __syncthreads(); }
  float s = red[0];
  float sb = e / s;
  sbout[b*256 + t] = sb;
  cs[t] = sb; __syncthreads();
  for (int o = 1; o < 256; o <<= 1){
    float v = cs[t];
    if (t >= o) v += cs[t - o];
    __syncthreads();
    cs[t] = v;
    __syncthreads();
  }
  float lc = logf(cs[t] + 1e-17f);
  float acc = (seg == 0) ? lc : (logcum[b*256 + t] + lc);
  logcum[b*256 + t] = acc;
  float mk = __expf(acc);
  maskf[b*256 + t] = mk;
  maskout[b*256 + t] = mk;
}

// ---------------------------------------------------------------- one-hot(lengths-1) (last segment)
__global__ void onehot_kernel(const int* __restrict__ lengths,
                              float* __restrict__ sbout)
{
  int b = blockIdx.x, t = threadIdx.x;
  sbout[b*256 + t] = (t == (lengths[b] - 1)) ? 1.0f : 0.0f;
}

// ---------------------------------------------------------------- launcher
extern "C" void kernel_launch(void* const* d_in, const int* in_sizes, int n_in,
                              void* d_out, int out_size, void* d_ws, size_t ws_size,
                              hipStream_t stream)
{
  const int*   actions = (const int*)d_in[0];
  const int*   lengths = (const int*)d_in[1];
  const float* gumbel  = (const float*)d_in[2];
  const float* epsz    = (const float*)d_in[3];
  const float* embed   = (const float*)d_in[4];
  const float* Wx      = (const float*)d_in[5];
  const float* Wh      = (const float*)d_in[6];
  const float* b_lstm  = (const float*)d_in[7];
  const float* Wz1     = (const float*)d_in[8];
  const float* bz1     = (const float*)d_in[9];
  const float* Wz2     = (const float*)d_in[10];
  const float* bz2     = (const float*)d_in[11];
  const float* Wb1     = (const float*)d_in[12];
  const float* bb1     = (const float*)d_in[13];
  const float* Wb2     = (const float*)d_in[14];
  const float* bb2     = (const float*)d_in[15];
  const float* Wd1     = (const float*)d_in[16];
  const float* bd1     = (const float*)d_in[17];
  const float* Wd2     = (const float*)d_in[18];
  const float* bd2     = (const float*)d_in[19];
  float* out = (float*)d_out;

  float* r2      = out + (size_t)REC_OFF + 2*(size_t)REC_SEG;
  ubf*   P       = (ubf*)(r2 + SCR_P);
  ubf*   hbuf    = (ubf*)(r2 + SCR_HBUF);
  u32*   flags   = (u32*)(r2 + SCR_FLAGS);
  float* maskf   = r2 + SCR_MASKF;
  float* logcum  = r2 + SCR_LOGCUM;
  float* partf   = r2 + SCR_PART;
  ubf*   encb    = (ubf*)(r2 + SCR_ENCB);

  hipLaunchKernelGGL(init_kernel, dim3(1), dim3(256), 0, stream, flags);

  hipLaunchKernelGGL(gemm_kernel, dim3(16, 4), dim3(256), 0, stream,
                     (const void*)embed, 1, Wx, b_lstm, P,
                     (const float*)nullptr, (float*)nullptr,
                     512, 2048, 512, 0, 499);

  for (int seg = 0; seg < 3; ++seg){
    int prev = (seg > 0) ? (seg - 1) : 0;
    hipLaunchKernelGGL(lstm_kernel, dim3((seg == 0) ? 64 : 128), dim3(256), 0, stream,
                       P, actions, Wh,
                       (seg == 0) ? (const float*)nullptr : maskf,
                       out + (size_t)seg * ENC_SEG,
                       (seg < 2) ? encb : (ubf*)nullptr,
                       hbuf, flags, seg,
                       // previous segment's tail (blocks 64..127):
                       out + (size_t)prev * ENC_SEG,
                       out + SAMB_OFF + (size_t)prev * 16384,
                       epsz + (size_t)prev * 4096,
                       Wz1, bz1, Wz2, bz2, Wd1, bd1, Wd2, bd2,
                       out + LOGZ_OFF + (size_t)prev * 8192,
                       out + SAMZ_OFF + (size_t)prev * 4096,
                       out + REC_OFF + (size_t)prev * REC_SEG);
    if (seg < 2){
      hipLaunchKernelGGL(gemm_kernel, dim3(4, 128), dim3(256), 0, stream,
                         (const void*)encb, 0, Wb1, bb1, (ubf*)nullptr, Wb2, partf,
                         16384, 512, 512, 1, 16383);
      hipLaunchKernelGGL(softmax_kernel, dim3(64), dim3(256), 0, stream,
                         partf, bb2, gumbel + (size_t)seg * 16384,
                         out + LOGB_OFF + (size_t)seg * 16384,
                         out + SAMB_OFF + (size_t)seg * 16384,
                         logcum, maskf, out + MASK_OFF + (size_t)seg * 16384, seg);
    } else {
      hipLaunchKernelGGL(onehot_kernel, dim3(64), dim3(256), 0, stream,
                         lengths, out + SAMB_OFF + (size_t)seg * 16384);
      hipLaunchKernelGGL(tail_kernel, dim3(64), dim3(256), 0, stream,
                         out + (size_t)seg * ENC_SEG,
                         out + SAMB_OFF + (size_t)seg * 16384,
                         Wz1, bz1, Wz2, bz2,
                         epsz + (size_t)seg * 4096,
                         Wd1, bd1, Wd2, bd2,
                         out + LOGZ_OFF + (size_t)seg * 8192,
                         out + SAMZ_OFF + (size_t)seg * 4096,
                         out + REC_OFF + (size_t)seg * REC_SEG);
    }
  }
  (void)in_sizes; (void)n_in; (void)out_size; (void)d_ws; (void)ws_size;
}

// Round 8
// 2202.901 us; speedup vs baseline: 1.1041x; 1.1041x over previous
//
#include <hip/hip_runtime.h>
#include <cstdint>
#include <cstddef>

typedef unsigned short ubf;   // bf16 bit pattern (internal use only)
typedef unsigned int   u32;
typedef __attribute__((ext_vector_type(8))) short short8;
typedef __attribute__((ext_vector_type(4))) float f32x4;
typedef __attribute__((ext_vector_type(4))) float f4v;
typedef __attribute__((ext_vector_type(2))) float f2v;
typedef __attribute__((ext_vector_type(4))) unsigned short us4;

#define NEG_INF_F (-1000000000.0f)
#define FOURH 2048

// d_out element offsets in FLOAT32 elements (confirmed r8/r9).
#define ENC_SEG   8388608            // 64*256*512
#define REC_OFF   25165824
#define REC_SEG   8192000            // 64*256*500
#define MASK_OFF  49741824
#define LOGB_OFF  49774592
#define SAMB_OFF  49807360
#define LOGZ_OFF  49856512
#define SAMZ_OFF  49881088

// scratch inside recs[2] dead region (f32 elements from region base).
// r18 replay-safety audit (zdec2 seg2 broadcast overwrites ALL of recs[2]):
//   P      — rewritten by gemm_P before lstm(0) reads          [next replay]
//   hbuf   — gated by flags; flags re-zeroed by init_kernel    [next replay]
//   maskf  — rewritten by softmax(0) before lstm(1) reads
//   logcum — rewritten (seg==0 path) before first read
//   partf  — rewritten by gemm_b before softmax reads
//   encb   — rewritten by lstm(0) before gemm_b(0) reads
#define SCR_P       0               // bf16[512][2048] = 524,288 f32
#define SCR_HBUF    524288          // bf16[2][4][16][512] = 32,768 f32
#define SCR_FLAGS   557056          // 1,024 f32 (64 flags x 16-dword padding)
#define SCR_MASKF   558080          // 16,384 f32
#define SCR_LOGCUM  574464          // 16,384 f32
#define SCR_PART    590848          // 131,072 f32
#define SCR_ENCB    1048576         // bf16[16384][512] = 4,194,304 f32

__device__ __forceinline__ float bf2f(ubf u){
  union { u32 i; float f; } v; v.i = ((u32)u) << 16; return v.f;
}
__device__ __forceinline__ ubf f2bf(float f){
  union { float f; u32 i; } v; v.f = f;
  u32 x = v.i;
  u32 r = (x + 0x7FFFu + ((x >> 16) & 1u)) >> 16;   // RNE
  return (ubf)r;
}
__device__ __forceinline__ float sigm(float x){
  return 1.0f / (1.0f + __expf(-x));
}
__device__ __forceinline__ float tanh_fast(float x){
  x = fminf(fmaxf(x, -20.0f), 20.0f);
  float e2 = __expf(2.0f * x);
  return (e2 - 1.0f) / (e2 + 1.0f);
}

// ---------------------------------------------------------------- init flags
__global__ void init_kernel(u32* flags){
  int tid = threadIdx.x;
  #pragma unroll
  for (int i = 0; i < 4; i++) flags[tid + i*256] = 0u;
}

// ---------------------------------------------------------------- GEMM (MFMA 16x16x32 bf16)
__global__ __launch_bounds__(256, 2) void gemm_kernel(
    const void* __restrict__ Aptr, int a_f32,
    const float* __restrict__ Bf, const float* __restrict__ bias,
    ubf* __restrict__ C, const float* __restrict__ wb2, float* __restrict__ part,
    int M, int N, int K, int relu, int mclamp)
{
  __shared__ __align__(16) ubf As[128*40];   // [128 rows][32 k + 8 pad]
  __shared__ __align__(16) ubf Bs[128*40];   // transposed: [128 n][32 k + 8 pad]
  int tid  = threadIdx.x;
  int bn   = blockIdx.x, bm = blockIdx.y;
  int w    = tid >> 6, lane = tid & 63, quad = lane >> 4, l16 = lane & 15;
  int wm   = w >> 1, wn = w & 1;

  f32x4 acc[4][4];
  #pragma unroll
  for (int i = 0; i < 4; i++)
    #pragma unroll
    for (int j = 0; j < 4; j++)
      #pragma unroll
      for (int r = 0; r < 4; r++) acc[i][j][r] = 0.0f;

  for (int k0 = 0; k0 < K; k0 += 32) {
    if (a_f32){
      const float* Af = (const float*)Aptr;
      #pragma unroll
      for (int h = 0; h < 4; h++){
        int v   = tid + h*256;          // 0..1023 float4 units
        int row = v >> 3, kc = (v & 7) * 4;
        int rm  = bm*128 + row;
        int ar  = rm < mclamp ? rm : mclamp;
        f4v q = *(const f4v*)(Af + (size_t)ar * K + k0 + kc);
        us4 s; s[0]=f2bf(q[0]); s[1]=f2bf(q[1]); s[2]=f2bf(q[2]); s[3]=f2bf(q[3]);
        *(us4*)&As[row*40 + kc] = s;
      }
    } else {
      const ubf* Ab = (const ubf*)Aptr;
      #pragma unroll
      for (int h = 0; h < 2; h++){
        int v   = tid + h*256;          // 0..511 vec8 units
        int row = v >> 2, kc = (v & 3) * 8;
        int rm  = bm*128 + row;
        int ar  = rm < mclamp ? rm : mclamp;
        uint4 q = *(const uint4*)(Ab + (size_t)ar * K + k0 + kc);
        *(uint4*)&As[row*40 + kc] = q;
      }
    }
    #pragma unroll
    for (int h = 0; h < 4; h++){
      int v  = tid + h*256;             // 0..1023 float4 units
      int kk = v >> 5, nn = (v & 31) * 4;
      f4v q = *(const f4v*)(Bf + (size_t)(k0 + kk) * N + bn*128 + nn);
      #pragma unroll
      for (int j = 0; j < 4; j++) Bs[(nn + j)*40 + kk] = f2bf(q[j]);
    }
    __syncthreads();
    short8 af[4], bfr[4];
    #pragma unroll
    for (int i = 0; i < 4; i++){
      int row = wm*64 + i*16 + l16;
      af[i]  = *(const short8*)&As[row*40 + quad*8];
      int col = wn*64 + i*16 + l16;
      bfr[i] = *(const short8*)&Bs[col*40 + quad*8];
    }
    #pragma unroll
    for (int i = 0; i < 4; i++)
      #pragma unroll
      for (int j = 0; j < 4; j++)
        acc[i][j] = __builtin_amdgcn_mfma_f32_16x16x32_bf16(af[i], bfr[j], acc[i][j], 0, 0, 0);
    __syncthreads();
  }
  if (!wb2){
    #pragma unroll
    for (int i = 0; i < 4; i++){
      #pragma unroll
      for (int j = 0; j < 4; j++){
        int n   = bn*128 + wn*64 + j*16 + l16;
        float bv = bias ? bias[n] : 0.0f;
        #pragma unroll
        for (int r = 0; r < 4; r++){
          int m   = bm*128 + wm*64 + i*16 + quad*4 + r;
          float vv = acc[i][j][r] + bv;
          if (relu) vv = fmaxf(vv, 0.0f);
          C[(size_t)m * N + n] = f2bf(vv);
        }
      }
    }
  } else {
    #pragma unroll
    for (int i = 0; i < 4; i++){
      f32x4 rp;
      #pragma unroll
      for (int r = 0; r < 4; r++) rp[r] = 0.0f;
      #pragma unroll
      for (int j = 0; j < 4; j++){
        int n   = bn*128 + wn*64 + j*16 + l16;
        float bv = bias[n];
        float wv = wb2[n];
        #pragma unroll
        for (int r = 0; r < 4; r++)
          rp[r] += fmaxf(acc[i][j][r] + bv, 0.0f) * wv;
      }
      #pragma unroll
      for (int off = 1; off < 16; off <<= 1)
        #pragma unroll
        for (int r = 0; r < 4; r++)
          rp[r] += __shfl_xor(rp[r], off, 64);
      if (l16 == 0){
        #pragma unroll
        for (int r = 0; r < 4; r++){
          int m = bm*128 + wm*64 + i*16 + quad*4 + r;
          part[(size_t)(bn*2 + wn)*16384 + m] = rp[r];
        }
      }
    }
  }
}

// ---------------------------------------------------------------- fused per-batch tail (segs 0/1, HIDDEN under next lstm):
// readout (r in LDS) -> z-head -> reparam -> decoder -> broadcast to all 256 rows.
// One block per batch, 256 threads. Runs on CUs idle during the 64-block lstm;
// its ~150us cost is fully hidden under the 611us lstm (r17-proven: lstm dur
// unchanged). All inputs complete before launch; writes only this batch's rec
// rows + lz/sz outputs — race-free without cross-block sync.
__device__ void tail_block(int b,
    const float* __restrict__ enc,    // [64][256][512] f32 (seg's enc)
    const float* __restrict__ sb_g,   // [64][256] f32 (seg's sample_b, FINAL out region)
    const float* __restrict__ Wz1, const float* __restrict__ bz1,
    const float* __restrict__ Wz2, const float* __restrict__ bz2,
    const float* __restrict__ epsz,   // seg's eps slice
    const float* __restrict__ Wd1, const float* __restrict__ bd1,
    const float* __restrict__ Wd2, const float* __restrict__ bd2,
    float* __restrict__ lzout, float* __restrict__ szout,
    float* __restrict__ recseg)
{
  __shared__ float sb[256];
  __shared__ float r[512];
  __shared__ float hz[512];
  __shared__ float lz[128];
  __shared__ float sz[64];
  __shared__ float hd[512];
  int tid = threadIdx.x;
  sb[tid] = sb_g[b*256 + tid];
  __syncthreads();
  // readout = sum_{t=0}^{254} enc[b,t,:] * sb[b,t+1]
  {
    const float* base = enc + ((size_t)b*256)*512 + tid*2;
    float a0 = 0.0f, a1 = 0.0f;
    for (int t = 0; t < 255; t++){
      float m = sb[t + 1];
      f2v q = *(const f2v*)(base + (size_t)t*512);
      a0 += m * q[0];
      a1 += m * q[1];
    }
    r[tid*2]     = a0;
    r[tid*2 + 1] = a1;
  }
  __syncthreads();
  {
    float a0 = bz1[tid], a1 = bz1[tid + 256];
    for (int i = 0; i < 512; i++){
      float ri = r[i];
      a0 += ri * Wz1[(size_t)i*512 + tid];
      a1 += ri * Wz1[(size_t)i*512 + tid + 256];
    }
    hz[tid]       = fmaxf(a0, 0.0f);
    hz[tid + 256] = fmaxf(a1, 0.0f);
  }
  __syncthreads();
  if (tid < 128){
    float a = bz2[tid];
    for (int i = 0; i < 512; i++) a += hz[i] * Wz2[(size_t)i*128 + tid];
    lz[tid] = a;
    lzout[b*128 + tid] = a;
  }
  __syncthreads();
  if (tid < 64){
    float mu = lz[tid], lv = lz[64 + tid];
    float v = mu + __expf(0.5f * lv) * epsz[b*64 + tid];
    sz[tid] = v;
    szout[b*64 + tid] = v;
  }
  __syncthreads();
  {
    float a0 = bd1[tid], a1 = bd1[tid + 256];
    for (int l = 0; l < 64; l++){
      float s = sz[l];
      a0 += s * Wd1[l*512 + tid];
      a1 += s * Wd1[l*512 + tid + 256];
    }
    hd[tid]       = fmaxf(a0, 0.0f);
    hd[tid + 256] = fmaxf(a1, 0.0f);
  }
  __syncthreads();
  {
    float a0 = bd2[tid];
    float a1 = (tid < 244) ? bd2[tid + 256] : 0.0f;
    for (int h = 0; h < 512; h++){
      float hh = hd[h];
      a0 += hh * Wd2[(size_t)h*500 + tid];
      if (tid < 244) a1 += hh * Wd2[(size_t)h*500 + tid + 256];
    }
    for (int t = 0; t < 256; t++){
      float* row = recseg + (size_t)b*128000 + (size_t)t*500;
      row[tid] = a0;
      if (tid < 244) row[tid + 256] = a1;
    }
  }
}

// ---------------------------------------------------------------- persistent masked-LSTM
// Protocol byte-identical to r12/r15/r16/r17 (608-615us across 4 runs; best of
// 5 protocols tried). Blocks 64..127 (segs 1,2) run the PREVIOUS segment's
// tail on otherwise-idle CUs — fully hidden (r17: lstm dur unchanged).
__global__ __launch_bounds__(256, 1) void lstm_kernel(
    const ubf* __restrict__ Pt,      // [512(V pad)][4H] bf16, includes b_lstm
    const int* __restrict__ actions, // [B][T]
    const float* __restrict__ Whf,   // [H][4H] f32
    const float* __restrict__ mask,  // [B][T] f32 or null (seg 0)
    float* __restrict__ enc,         // d_out + seg*ENC_SEG (f32)
    ubf* __restrict__ encb,          // scratch bf16 enc copy or null (seg 2)
    ubf* hbuf,                       // scratch: [2][4][16][512] bf16
    u32* flags,                      // scratch: [64]x16-dword-padded
    int seg,
    // ---- fused tail (previous segment) args; used by blocks >= 64 ----
    const float* __restrict__ tenc, const float* __restrict__ tsb,
    const float* __restrict__ teps,
    const float* __restrict__ Wz1, const float* __restrict__ bz1,
    const float* __restrict__ Wz2, const float* __restrict__ bz2,
    const float* __restrict__ Wd1, const float* __restrict__ bd1,
    const float* __restrict__ Wd2, const float* __restrict__ bd2,
    float* __restrict__ tlz, float* __restrict__ tsz, float* __restrict__ trec)
{
  if (blockIdx.x >= 64){
    tail_block(blockIdx.x - 64, tenc, tsb, Wz1, bz1, Wz2, bz2, teps,
               Wd1, bd1, Wd2, bd2, tlz, tsz, trec);
    return;
  }
  __shared__ __align__(16) ubf   htile[16*520];   // [16 b][512 + 8 pad]
  __shared__ __align__(16) ubf   ptile[16*136];   // [16 b][128 + 8 pad]
  __shared__ __align__(16) float ztile[16*132];   // [16 b][128 + 4 pad]

  int tid  = threadIdx.x;
  int wv   = tid >> 6;            // wave = gate index 0..3 (i,f,g,o)
  int lane = tid & 63, quad = lane >> 4, l16 = lane & 15;
  int bg   = blockIdx.x >> 4, cg = blockIdx.x & 15;
  int j0   = cg * 32;             // unit base

  // persistent Wh B-fragments: B[k][n], n = lane&15, k = quad*8+j
  short8 bfrag[2][16];
  #pragma unroll
  for (int h = 0; h < 2; h++){
    int col = wv*512 + j0 + h*16 + l16;
    #pragma unroll
    for (int kt = 0; kt < 16; kt++){
      short8 t8;
      #pragma unroll
      for (int j = 0; j < 8; j++){
        int k = kt*32 + quad*8 + j;
        t8[j] = (short)f2bf(Whf[(size_t)k * FOURH + col]);
      }
      bfrag[h][kt] = t8;
    }
  }

  float cst0 = 0.0f, cst1 = 0.0f;      // c-state for this thread's 2 (batch,unit) pairs
  int bl = tid >> 4;                   // local batch 0..15
  int up = (tid & 15) * 2;             // unit pair base within 32
  int bglob = bg*16 + bl;
  u32* htile32 = (u32*)htile;
  unsigned epoch0 = (unsigned)seg * 256u;
  u32* myflag = &flags[(bg*16 + (tid >> 4))*16];   // producer block this thread reads

  for (int t = 0; t < 256; ++t){
    // stage P tile [16 b][4 gates x 32 units], gathered by action id (L2-resident);
    // issued first so its latency hides under the flag poll below.
    {
      int act  = actions[(size_t)bglob * 256 + t];
      int colc = (tid & 15) * 8;
      int gate = colc >> 5, cw = colc & 31;
      uint4 q = *(const uint4*)(Pt + (size_t)act * FOURH + gate*512 + j0 + cw);
      *(uint4*)&ptile[bl*136 + colc] = q;
    }
    if (t > 0){
      // each thread polls the ONE producer flag it depends on, then loads its
      // 16 words (word index tid of 16 rows, all from block cg'=tid>>4).
      unsigned tgt = epoch0 + (unsigned)t;
      while (__hip_atomic_load(myflag, __ATOMIC_RELAXED, __HIP_MEMORY_SCOPE_AGENT) < tgt)
        __builtin_amdgcn_s_sleep(1);
      const u32* src = (const u32*)(hbuf + (size_t)(((t+1)&1)*4 + bg) * 16 * 512);
      u32 tmp[16];
      #pragma unroll
      for (int i = 0; i < 16; i++)
        tmp[i] = __hip_atomic_load(&src[tid + 256*i], __ATOMIC_RELAXED, __HIP_MEMORY_SCOPE_AGENT);
      #pragma unroll
      for (int i = 0; i < 16; i++)
        htile32[i*260 + tid] = tmp[i];     // row i = batch, 260 u32/row (padded)
    }
    __syncthreads();   // sync A: htile (and ptile) staged for this step

    f32x4 a0, a1;
    #pragma unroll
    for (int r = 0; r < 4; r++){ a0[r] = 0.0f; a1[r] = 0.0f; }
    if (t > 0){
      #pragma unroll
      for (int kt = 0; kt < 16; kt++){
        short8 af = *(const short8*)&htile[l16*520 + kt*32 + quad*8];
        a0 = __builtin_amdgcn_mfma_f32_16x16x32_bf16(af, bfrag[0][kt], a0, 0, 0, 0);
        a1 = __builtin_amdgcn_mfma_f32_16x16x32_bf16(af, bfrag[1][kt], a1, 0, 0, 0);
      }
    }
    // redistribute z via LDS so each thread gets matching i,f,g,o
    #pragma unroll
    for (int r = 0; r < 4; r++){
      ztile[(quad*4 + r)*132 + wv*32 + l16]      = a0[r];
      ztile[(quad*4 + r)*132 + wv*32 + 16 + l16] = a1[r];
    }
    __syncthreads();   // sync B: ztile ready for elementwise

    float m = mask ? mask[(size_t)bglob * 256 + t] : 1.0f;
    f2v ev;
    ubf hp[2];
    #pragma unroll
    for (int p = 0; p < 2; p++){
      int u = up + p;
      float zi = ztile[bl*132 +       u] + bf2f(ptile[bl*136 +       u]);
      float zf = ztile[bl*132 + 32 + u] + bf2f(ptile[bl*136 + 32 + u]);
      float zg = ztile[bl*132 + 64 + u] + bf2f(ptile[bl*136 + 64 + u]);
      float zo = ztile[bl*132 + 96 + u] + bf2f(ptile[bl*136 + 96 + u]);
      float is = sigm(zi), fs = sigm(zf), gt = tanh_fast(zg), os = sigm(zo);
      float cp = p ? cst1 : cst0;
      float cn = fs * cp + is * gt;
      float hn = os * tanh_fast(cn);
      ev[p] = hn;                       // enc records PRE-mask h (f32)
      float cm = m * cn;
      if (p) cst1 = cm; else cst0 = cm;
      hp[p] = f2bf(m * hn);             // masked h carried forward (bf16)
    }
    {
      u32 hword = (u32)hp[0] | ((u32)hp[1] << 16);
      u32* dst = (u32*)(hbuf + (size_t)((t&1)*4 + bg) * 16 * 512);
      __hip_atomic_store(&dst[(bl*512 + j0 + up) >> 1], hword,
                         __ATOMIC_RELAXED, __HIP_MEMORY_SCOPE_AGENT);
    }
    __threadfence_block();   // ordering intent only (block scope: no cache ops)
    __syncthreads();         // drain: vmcnt(0) -> sc1 h-stores committed at L3
    if (tid == 0)
      __hip_atomic_store(&flags[(bg*16 + cg)*16], epoch0 + (unsigned)t + 1u,
                         __ATOMIC_RELAXED, __HIP_MEMORY_SCOPE_AGENT);
    // enc stores AFTER the announce: HBM acks off the protocol path; they
    // drain during the next step's poll window (covered by next drain).
    *(f2v*)(enc + ((size_t)bglob * 256 + t) * 512 + j0 + up) = ev;
    if (encb){
      u32 ebw = (u32)f2bf(ev[0]) | ((u32)f2bf(ev[1]) << 16);
      *(u32*)&encb[((size_t)bglob * 256 + t) * 512 + j0 + up] = ebw;
    }
  }
}

// ---------------------------------------------------------------- seg2 tail: one-hot readout collapses
// to a single enc-row gather: sb(2)=onehot(lengths-1) => readout[b] =
// (lengths[b]>=2) ? enc[b, lengths[b]-2, :] : 0. Then the r15-proven
// 512-thread zdec phases, then cooperative LDS->global broadcast of the
// 500-float pred row to all 256 timesteps (f4v, coalesced). No rof scratch:
// reads only out-region/input data, writes only this batch's rows — the
// recs[2] full-region broadcast is race-free (r16's objection was rof).
__global__ __launch_bounds__(512, 1) void zdec2_kernel(
    const float* __restrict__ enc, const int* __restrict__ lengths,
    const float* __restrict__ Wz1, const float* __restrict__ bz1,
    const float* __restrict__ Wz2, const float* __restrict__ bz2,
    const float* __restrict__ epsz,
    const float* __restrict__ Wd1, const float* __restrict__ bd1,
    const float* __restrict__ Wd2, const float* __restrict__ bd2,
    float* __restrict__ lzout, float* __restrict__ szout, float* __restrict__ recseg)
{
  __shared__ float r[512], hz[512], lz[128], sz[64], hd[512];
  __shared__ __align__(16) float row[500];
  int b = blockIdx.x, tid = threadIdx.x;
  int L = lengths[b];
  r[tid] = (L >= 2) ? enc[((size_t)b*256 + (L - 2))*512 + tid] : 0.0f;
  __syncthreads();
  {
    float a0 = bz1[tid];
    for (int i = 0; i < 512; i++)
      a0 += r[i] * Wz1[(size_t)i*512 + tid];
    hz[tid] = fmaxf(a0, 0.0f);
  }
  __syncthreads();
  if (tid < 128){
    float a = bz2[tid];
    for (int i = 0; i < 512; i++) a += hz[i] * Wz2[(size_t)i*128 + tid];
    lz[tid] = a;
    lzout[b*128 + tid] = a;
  }
  __syncthreads();
  if (tid < 64){
    float mu = lz[tid], lv = lz[64 + tid];
    float v = mu + __expf(0.5f * lv) * epsz[b*64 + tid];
    sz[tid] = v;
    szout[b*64 + tid] = v;
  }
  __syncthreads();
  {
    float a0 = bd1[tid];
    for (int l = 0; l < 64; l++)
      a0 += sz[l] * Wd1[l*512 + tid];
    hd[tid] = fmaxf(a0, 0.0f);
  }
  __syncthreads();
  if (tid < 500){
    float a0 = bd2[tid];
    for (int h = 0; h < 512; h++)
      a0 += hd[h] * Wd2[(size_t)h*500 + tid];
    row[tid] = a0;
  }
  __syncthreads();
  // broadcast: 256 rows x 125 f4v units = 32000 vec stores per block
  for (int i = tid; i < 256*125; i += 512){
    int t = i / 125, c = i - t*125;
    *(f4v*)(recseg + (size_t)b*128000 + (size_t)t*500 + c*4) = *(const f4v*)&row[c*4];
  }
}

// ---------------------------------------------------------------- softmax + cumsum + mask update (per batch)
__global__ __launch_bounds__(256, 4) void softmax_kernel(
    const float* __restrict__ part, const float* __restrict__ bb2, const float* __restrict__ gum,
    float* __restrict__ lout,
    float* __restrict__ sbout,
    float* __restrict__ logcum, float* __restrict__ maskf, float* __restrict__ maskout,
    int seg)
{
  __shared__ float red[256];
  __shared__ float cs[256];
  int b = blockIdx.x, t = threadIdx.x;
  float raw = 0.0f;
  #pragma unroll
  for (int s = 0; s < 8; s++) raw += part[s*16384 + b*256 + t];
  float lg  = (t == 0) ? NEG_INF_F : (raw + bb2[0]);
  lout[b*256 + t] = lg;
  float x = lg + gum[b*256 + t];   // TEMP_B = 1
  red[t] = x; __syncthreads();
  for (int o = 128; o > 0; o >>= 1){ if (t < o) red[t] = fmaxf(red[t], red[t+o]); __syncthreads(); }
  float mx = red[0]; __syncthreads();
  float e = __expf(x - mx);
  red[t] = e; __syncthreads();
  for (int o = 128; o > 0; o >>= 1){ if (t < o) red[t] += red[t+o]; __syncthreads(); }
  float s = red[0];
  float sb = e / s;
  sbout[b*256 + t] = sb;
  cs[t] = sb; __syncthreads();
  for (int o = 1; o < 256; o <<= 1){
    float v = cs[t];
    if (t >= o) v += cs[t - o];
    __syncthreads();
    cs[t] = v;
    __syncthreads();
  }
  float lc = logf(cs[t] + 1e-17f);
  float acc = (seg == 0) ? lc : (logcum[b*256 + t] + lc);
  logcum[b*256 + t] = acc;
  float mk = __expf(acc);
  maskf[b*256 + t] = mk;
  maskout[b*256 + t] = mk;
}

// ---------------------------------------------------------------- one-hot(lengths-1) (last segment)
__global__ void onehot_kernel(const int* __restrict__ lengths,
                              float* __restrict__ sbout)
{
  int b = blockIdx.x, t = threadIdx.x;
  sbout[b*256 + t] = (t == (lengths[b] - 1)) ? 1.0f : 0.0f;
}

// ---------------------------------------------------------------- launcher
extern "C" void kernel_launch(void* const* d_in, const int* in_sizes, int n_in,
                              void* d_out, int out_size, void* d_ws, size_t ws_size,
                              hipStream_t stream)
{
  const int*   actions = (const int*)d_in[0];
  const int*   lengths = (const int*)d_in[1];
  const float* gumbel  = (const float*)d_in[2];
  const float* epsz    = (const float*)d_in[3];
  const float* embed   = (const float*)d_in[4];
  const float* Wx      = (const float*)d_in[5];
  const float* Wh      = (const float*)d_in[6];
  const float* b_lstm  = (const float*)d_in[7];
  const float* Wz1     = (const float*)d_in[8];
  const float* bz1     = (const float*)d_in[9];
  const float* Wz2     = (const float*)d_in[10];
  const float* bz2     = (const float*)d_in[11];
  const float* Wb1     = (const float*)d_in[12];
  const float* bb1     = (const float*)d_in[13];
  const float* Wb2     = (const float*)d_in[14];
  const float* bb2     = (const float*)d_in[15];
  const float* Wd1     = (const float*)d_in[16];
  const float* bd1     = (const float*)d_in[17];
  const float* Wd2     = (const float*)d_in[18];
  const float* bd2     = (const float*)d_in[19];
  float* out = (float*)d_out;

  float* r2      = out + (size_t)REC_OFF + 2*(size_t)REC_SEG;
  ubf*   P       = (ubf*)(r2 + SCR_P);
  ubf*   hbuf    = (ubf*)(r2 + SCR_HBUF);
  u32*   flags   = (u32*)(r2 + SCR_FLAGS);
  float* maskf   = r2 + SCR_MASKF;
  float* logcum  = r2 + SCR_LOGCUM;
  float* partf   = r2 + SCR_PART;
  ubf*   encb    = (ubf*)(r2 + SCR_ENCB);

  hipLaunchKernelGGL(init_kernel, dim3(1), dim3(256), 0, stream, flags);

  hipLaunchKernelGGL(gemm_kernel, dim3(16, 4), dim3(256), 0, stream,
                     (const void*)embed, 1, Wx, b_lstm, P,
                     (const float*)nullptr, (float*)nullptr,
                     512, 2048, 512, 0, 499);

  for (int seg = 0; seg < 3; ++seg){
    int prev = (seg > 0) ? (seg - 1) : 0;
    hipLaunchKernelGGL(lstm_kernel, dim3((seg == 0) ? 64 : 128), dim3(256), 0, stream,
                       P, actions, Wh,
                       (seg == 0) ? (const float*)nullptr : maskf,
                       out + (size_t)seg * ENC_SEG,
                       (seg < 2) ? encb : (ubf*)nullptr,
                       hbuf, flags, seg,
                       // previous segment's tail (blocks 64..127):
                       out + (size_t)prev * ENC_SEG,
                       out + SAMB_OFF + (size_t)prev * 16384,
                       epsz + (size_t)prev * 4096,
                       Wz1, bz1, Wz2, bz2, Wd1, bd1, Wd2, bd2,
                       out + LOGZ_OFF + (size_t)prev * 8192,
                       out + SAMZ_OFF + (size_t)prev * 4096,
                       out + REC_OFF + (size_t)prev * REC_SEG);
    if (seg < 2){
      hipLaunchKernelGGL(gemm_kernel, dim3(4, 128), dim3(256), 0, stream,
                         (const void*)encb, 0, Wb1, bb1, (ubf*)nullptr, Wb2, partf,
                         16384, 512, 512, 1, 16383);
      hipLaunchKernelGGL(softmax_kernel, dim3(64), dim3(256), 0, stream,
                         partf, bb2, gumbel + (size_t)seg * 16384,
                         out + LOGB_OFF + (size_t)seg * 16384,
                         out + SAMB_OFF + (size_t)seg * 16384,
                         logcum, maskf, out + MASK_OFF + (size_t)seg * 16384, seg);
    } else {
      hipLaunchKernelGGL(onehot_kernel, dim3(64), dim3(256), 0, stream,
                         lengths, out + SAMB_OFF + (size_t)seg * 16384);
      hipLaunchKernelGGL(zdec2_kernel, dim3(64), dim3(512), 0, stream,
                         out + (size_t)seg * ENC_SEG, lengths,
                         Wz1, bz1, Wz2, bz2,
                         epsz + (size_t)seg * 4096,
                         Wd1, bd1, Wd2, bd2,
                         out + LOGZ_OFF + (size_t)seg * 8192,
                         out + SAMZ_OFF + (size_t)seg * 4096,
                         out + REC_OFF + (size_t)seg * REC_SEG);
    }
  }
  (void)in_sizes; (void)n_in; (void)out_size; (void)d_ws; (void)ws_size;
}

// Round 9
// 2175.853 us; speedup vs baseline: 1.1178x; 1.0124x over previous
//
#include <hip/hip_runtime.h>
#include <cstdint>
#include <cstddef>

typedef unsigned short ubf;   // bf16 bit pattern (internal use only)
typedef unsigned int   u32;
typedef __attribute__((ext_vector_type(8))) short short8;
typedef __attribute__((ext_vector_type(4))) float f32x4;
typedef __attribute__((ext_vector_type(4))) float f4v;
typedef __attribute__((ext_vector_type(2))) float f2v;
typedef __attribute__((ext_vector_type(4))) unsigned short us4;

#define NEG_INF_F (-1000000000.0f)
#define FOURH 2048

// d_out element offsets in FLOAT32 elements (confirmed r8/r9).
#define ENC_SEG   8388608            // 64*256*512
#define REC_OFF   25165824
#define REC_SEG   8192000            // 64*256*500
#define MASK_OFF  49741824
#define LOGB_OFF  49774592
#define SAMB_OFF  49807360
#define LOGZ_OFF  49856512
#define SAMZ_OFF  49881088

// scratch inside recs[2] dead region (f32 elements from region base).
// Replay-safety: flags/sent/cnt re-zeroed by init each replay; P rewritten by
// gemm_P before lstm(0); maskf/logcum rewritten by softmax(0) before reads;
// partf rewritten by gemm role before softmax reads; encb rewritten by lstm(0)
// before gemm role reads. zdec2's seg2 broadcast overwrites all of recs[2]
// only after every scratch consumer is done.
#define SCR_P       0               // bf16[512][2048] = 524,288 f32
#define SCR_HBUF    524288          // bf16[2][4][16][512] = 32,768 f32
#define SCR_FLAGS   557056          // 1,024 f32 (64 flags x 16-dword padding)
#define SCR_MASKF   558080          // 16,384 f32
#define SCR_LOGCUM  574464          // 16,384 f32
#define SCR_PART    590848          // 131,072 f32
#define SCR_SENT    721920          // 1,024 f32 (64 sentinels x 16-dword padding)
#define SCR_CNT     722944          // 32 f32 (2 counters x 16-dword padding)
#define SCR_ENCB    1048576         // bf16[16384][512] = 4,194,304 f32 (t-major: m=t*64+b)

__device__ __forceinline__ float bf2f(ubf u){
  union { u32 i; float f; } v; v.i = ((u32)u) << 16; return v.f;
}
__device__ __forceinline__ ubf f2bf(float f){
  union { float f; u32 i; } v; v.f = f;
  u32 x = v.i;
  u32 r = (x + 0x7FFFu + ((x >> 16) & 1u)) >> 16;   // RNE
  return (ubf)r;
}
__device__ __forceinline__ float sigm(float x){
  return 1.0f / (1.0f + __expf(-x));
}
__device__ __forceinline__ float tanh_fast(float x){
  x = fminf(fmaxf(x, -20.0f), 20.0f);
  float e2 = __expf(2.0f * x);
  return (e2 - 1.0f) / (e2 + 1.0f);
}

// ---------------------------------------------------------------- init flags + sentinels + counters
__global__ void init_kernel(u32* flags, u32* sent, u32* cnt){
  int tid = threadIdx.x;
  #pragma unroll
  for (int i = 0; i < 4; i++){ flags[tid + i*256] = 0u; sent[tid + i*256] = 0u; }
  if (tid < 32) cnt[tid] = 0u;
}

// ---------------------------------------------------------------- GEMM (MFMA 16x16x32 bf16) — used for gemm_P only
__global__ __launch_bounds__(256, 2) void gemm_kernel(
    const void* __restrict__ Aptr, int a_f32,
    const float* __restrict__ Bf, const float* __restrict__ bias,
    ubf* __restrict__ C, const float* __restrict__ wb2, float* __restrict__ part,
    int M, int N, int K, int relu, int mclamp)
{
  __shared__ __align__(16) ubf As[128*40];   // [128 rows][32 k + 8 pad]
  __shared__ __align__(16) ubf Bs[128*40];   // transposed: [128 n][32 k + 8 pad]
  int tid  = threadIdx.x;
  int bn   = blockIdx.x, bm = blockIdx.y;
  int w    = tid >> 6, lane = tid & 63, quad = lane >> 4, l16 = lane & 15;
  int wm   = w >> 1, wn = w & 1;

  f32x4 acc[4][4];
  #pragma unroll
  for (int i = 0; i < 4; i++)
    #pragma unroll
    for (int j = 0; j < 4; j++)
      #pragma unroll
      for (int r = 0; r < 4; r++) acc[i][j][r] = 0.0f;

  for (int k0 = 0; k0 < K; k0 += 32) {
    if (a_f32){
      const float* Af = (const float*)Aptr;
      #pragma unroll
      for (int h = 0; h < 4; h++){
        int v   = tid + h*256;          // 0..1023 float4 units
        int row = v >> 3, kc = (v & 7) * 4;
        int rm  = bm*128 + row;
        int ar  = rm < mclamp ? rm : mclamp;
        f4v q = *(const f4v*)(Af + (size_t)ar * K + k0 + kc);
        us4 s; s[0]=f2bf(q[0]); s[1]=f2bf(q[1]); s[2]=f2bf(q[2]); s[3]=f2bf(q[3]);
        *(us4*)&As[row*40 + kc] = s;
      }
    } else {
      const ubf* Ab = (const ubf*)Aptr;
      #pragma unroll
      for (int h = 0; h < 2; h++){
        int v   = tid + h*256;          // 0..511 vec8 units
        int row = v >> 2, kc = (v & 3) * 8;
        int rm  = bm*128 + row;
        int ar  = rm < mclamp ? rm : mclamp;
        uint4 q = *(const uint4*)(Ab + (size_t)ar * K + k0 + kc);
        *(uint4*)&As[row*40 + kc] = q;
      }
    }
    #pragma unroll
    for (int h = 0; h < 4; h++){
      int v  = tid + h*256;             // 0..1023 float4 units
      int kk = v >> 5, nn = (v & 31) * 4;
      f4v q = *(const f4v*)(Bf + (size_t)(k0 + kk) * N + bn*128 + nn);
      #pragma unroll
      for (int j = 0; j < 4; j++) Bs[(nn + j)*40 + kk] = f2bf(q[j]);
    }
    __syncthreads();
    short8 af[4], bfr[4];
    #pragma unroll
    for (int i = 0; i < 4; i++){
      int row = wm*64 + i*16 + l16;
      af[i]  = *(const short8*)&As[row*40 + quad*8];
      int col = wn*64 + i*16 + l16;
      bfr[i] = *(const short8*)&Bs[col*40 + quad*8];
    }
    #pragma unroll
    for (int i = 0; i < 4; i++)
      #pragma unroll
      for (int j = 0; j < 4; j++)
        acc[i][j] = __builtin_amdgcn_mfma_f32_16x16x32_bf16(af[i], bfr[j], acc[i][j], 0, 0, 0);
    __syncthreads();
  }
  #pragma unroll
  for (int i = 0; i < 4; i++){
    #pragma unroll
    for (int j = 0; j < 4; j++){
      int n   = bn*128 + wn*64 + j*16 + l16;
      float bv = bias ? bias[n] : 0.0f;
      #pragma unroll
      for (int r = 0; r < 4; r++){
        int m   = bm*128 + wm*64 + i*16 + quad*4 + r;
        float vv = acc[i][j][r] + bv;
        if (relu) vv = fmaxf(vv, 0.0f);
        C[(size_t)m * N + n] = f2bf(vv);
      }
    }
  }
  (void)wb2; (void)part; (void)M;
}

// ---------------------------------------------------------------- fused per-batch tail (prev seg, HIDDEN under lstm):
// readout -> z-head -> reparam -> decoder -> broadcast. One block per batch.
// r17-proven: rides idle CUs, lstm dur unchanged. smem is the shared carve.
__device__ void tail_block(char* smem, int b,
    const float* __restrict__ enc, const float* __restrict__ sb_g,
    const float* __restrict__ Wz1, const float* __restrict__ bz1,
    const float* __restrict__ Wz2, const float* __restrict__ bz2,
    const float* __restrict__ epsz,
    const float* __restrict__ Wd1, const float* __restrict__ bd1,
    const float* __restrict__ Wd2, const float* __restrict__ bd2,
    float* __restrict__ lzout, float* __restrict__ szout,
    float* __restrict__ recseg)
{
  float* sb = (float*)smem;            // 256
  float* r  = sb + 256;                // 512
  float* hz = r + 512;                 // 512
  float* lz = hz + 512;                // 128
  float* sz = lz + 128;                // 64
  float* hd = sz + 64;                 // 512   (total 7936 B)
  int tid = threadIdx.x;
  sb[tid] = sb_g[b*256 + tid];
  __syncthreads();
  {
    const float* base = enc + ((size_t)b*256)*512 + tid*2;
    float a0 = 0.0f, a1 = 0.0f;
    for (int t = 0; t < 255; t++){
      float m = sb[t + 1];
      f2v q = *(const f2v*)(base + (size_t)t*512);
      a0 += m * q[0];
      a1 += m * q[1];
    }
    r[tid*2]     = a0;
    r[tid*2 + 1] = a1;
  }
  __syncthreads();
  {
    float a0 = bz1[tid], a1 = bz1[tid + 256];
    for (int i = 0; i < 512; i++){
      float ri = r[i];
      a0 += ri * Wz1[(size_t)i*512 + tid];
      a1 += ri * Wz1[(size_t)i*512 + tid + 256];
    }
    hz[tid]       = fmaxf(a0, 0.0f);
    hz[tid + 256] = fmaxf(a1, 0.0f);
  }
  __syncthreads();
  if (tid < 128){
    float a = bz2[tid];
    for (int i = 0; i < 512; i++) a += hz[i] * Wz2[(size_t)i*128 + tid];
    lz[tid] = a;
    lzout[b*128 + tid] = a;
  }
  __syncthreads();
  if (tid < 64){
    float mu = lz[tid], lv = lz[64 + tid];
    float v = mu + __expf(0.5f * lv) * epsz[b*64 + tid];
    sz[tid] = v;
    szout[b*64 + tid] = v;
  }
  __syncthreads();
  {
    float a0 = bd1[tid], a1 = bd1[tid + 256];
    for (int l = 0; l < 64; l++){
      float s = sz[l];
      a0 += s * Wd1[l*512 + tid];
      a1 += s * Wd1[l*512 + tid + 256];
    }
    hd[tid]       = fmaxf(a0, 0.0f);
    hd[tid + 256] = fmaxf(a1, 0.0f);
  }
  __syncthreads();
  {
    float a0 = bd2[tid];
    float a1 = (tid < 244) ? bd2[tid + 256] : 0.0f;
    for (int h = 0; h < 512; h++){
      float hh = hd[h];
      a0 += hh * Wd2[(size_t)h*500 + tid];
      if (tid < 244) a1 += hh * Wd2[(size_t)h*500 + tid + 256];
    }
    for (int t = 0; t < 256; t++){
      float* row = recseg + (size_t)b*128000 + (size_t)t*500;
      row[tid] = a0;
      if (tid < 244) row[tid + 256] = a1;
    }
  }
}

// ---------------------------------------------------------------- mega kernel: role-switched fused launch
// Roles by blockIdx (seg0 grid 640, seg1 grid 704, seg2 grid 128):
//   [0..63]              lstm(seg)            — protocol byte-identical to r12..r18
//   [64..127]   (seg>=1) tail(seg-1)          — r17-proven hidden
//   [gb..gb+511](seg<2)  b-head gemm(seg)     — gated on h-flags: encb(t) is
//                        guaranteed committed once flag >= epoch0+t+2 (the
//                        NEXT step's drain-barrier drains it); t=255 rows use
//                        the post-loop sentinel. encb is t-major (m=t*64+b) so
//                        tile bm covers timesteps {2bm, 2bm+1} — work spreads
//                        across the lstm's runtime.
//   [gb+512..+575](seg<2) softmax(seg)        — polls gemm-done counter.
// Cross-XCD intra-launch visibility: encb & part stores are sc1 (relaxed
// agent); readers first-touch after their gate -> fetch fresh from L3.
// maskf(seg) is complete before launch(seg+1) -> cross-launch protocol
// unchanged, lstm needs no mask gating.
__global__ __launch_bounds__(256, 1) void mega_kernel(
    int seg,
    // lstm
    const ubf* __restrict__ Pt, const int* __restrict__ actions,
    const float* __restrict__ Whf, const float* __restrict__ mask,
    float* __restrict__ enc, ubf* __restrict__ encb,
    ubf* hbuf, u32* flags, u32* sent,
    // b-head gemm (current seg)
    const float* __restrict__ Wb1, const float* __restrict__ bb1,
    const float* __restrict__ Wb2f, float* __restrict__ part, u32* gemmcnt,
    // softmax (current seg)
    const float* __restrict__ bb2, const float* __restrict__ gum,
    float* __restrict__ lout, float* __restrict__ sbout,
    float* __restrict__ logcum, float* __restrict__ maskf, float* __restrict__ maskoutp,
    // tail (prev seg)
    const float* __restrict__ tenc, const float* __restrict__ tsb,
    const float* __restrict__ teps,
    const float* __restrict__ Wz1, const float* __restrict__ bz1,
    const float* __restrict__ Wz2, const float* __restrict__ bz2,
    const float* __restrict__ Wd1, const float* __restrict__ bd1,
    const float* __restrict__ Wd2, const float* __restrict__ bd2,
    float* __restrict__ tlz, float* __restrict__ tsz, float* __restrict__ trec)
{
  __shared__ __align__(16) char smem[29696];
  int bx  = threadIdx.y ? 0 : blockIdx.x;   // (threadIdx.y always 0; keeps smem "used" uniformly)
  int tid = threadIdx.x;
  unsigned epoch0 = (unsigned)seg * 256u;
  int gemm_base = (seg == 0) ? 64 : 128;

  // ---------------- tail role ----------------
  if (seg >= 1 && bx >= 64 && bx < 128){
    tail_block(smem, bx - 64, tenc, tsb, Wz1, bz1, Wz2, bz2, teps,
               Wd1, bd1, Wd2, bd2, tlz, tsz, trec);
    return;
  }

  // ---------------- b-head gemm role ----------------
  if (seg < 2 && bx >= gemm_base && bx < gemm_base + 512){
    int gb = bx - gemm_base;
    int bn = gb & 3, bm = gb >> 2;          // bn: 4 col-tiles of 128; bm: 128 row-tiles
    // gate: rows are timesteps {2bm, 2bm+1} of ALL 64 batches -> poll all 64 flags.
    {
      int need = bm*2 + 3;                  // t_max + 2
      unsigned tgt = epoch0 + (unsigned)(need > 256 ? 256 : need);
      if (tid < 64){
        while (__hip_atomic_load(&flags[tid*16], __ATOMIC_RELAXED, __HIP_MEMORY_SCOPE_AGENT) < tgt)
          __builtin_amdgcn_s_sleep(16);
        if (bm == 127){
          while (__hip_atomic_load(&sent[tid*16], __ATOMIC_RELAXED, __HIP_MEMORY_SCOPE_AGENT) < (u32)(seg + 1))
            __builtin_amdgcn_s_sleep(16);
        }
      }
      __syncthreads();
    }
    ubf* As = (ubf*)smem;                   // [128][40]
    ubf* Bs = (ubf*)smem + 128*40;          // [128][40]
    int w = tid >> 6, lane = tid & 63, quad = lane >> 4, l16 = lane & 15;
    int wm = w >> 1, wn = w & 1;
    f32x4 acc[4][4];
    #pragma unroll
    for (int i = 0; i < 4; i++)
      #pragma unroll
      for (int j = 0; j < 4; j++)
        #pragma unroll
        for (int r = 0; r < 4; r++) acc[i][j][r] = 0.0f;
    for (int k0 = 0; k0 < 512; k0 += 32){
      #pragma unroll
      for (int h = 0; h < 2; h++){
        int v   = tid + h*256;              // 0..511 vec8 units
        int row = v >> 2, kc = (v & 3) * 8;
        int m   = bm*128 + row;
        uint4 q = *(const uint4*)(encb + (size_t)m * 512 + k0 + kc);
        *(uint4*)&As[row*40 + kc] = q;
      }
      #pragma unroll
      for (int h = 0; h < 4; h++){
        int v  = tid + h*256;
        int kk = v >> 5, nn = (v & 31) * 4;
        f4v q = *(const f4v*)(Wb1 + (size_t)(k0 + kk) * 512 + bn*128 + nn);
        #pragma unroll
        for (int j = 0; j < 4; j++) Bs[(nn + j)*40 + kk] = f2bf(q[j]);
      }
      __syncthreads();
      short8 af[4], bfr[4];
      #pragma unroll
      for (int i = 0; i < 4; i++){
        af[i]  = *(const short8*)&As[(wm*64 + i*16 + l16)*40 + quad*8];
        bfr[i] = *(const short8*)&Bs[(wn*64 + i*16 + l16)*40 + quad*8];
      }
      #pragma unroll
      for (int i = 0; i < 4; i++)
        #pragma unroll
        for (int j = 0; j < 4; j++)
          acc[i][j] = __builtin_amdgcn_mfma_f32_16x16x32_bf16(af[i], bfr[j], acc[i][j], 0, 0, 0);
      __syncthreads();
    }
    // epilogue: relu(acc+bb1) dot Wb2 over n, lane-reduce, sc1 part store
    #pragma unroll
    for (int i = 0; i < 4; i++){
      f32x4 rp;
      #pragma unroll
      for (int r = 0; r < 4; r++) rp[r] = 0.0f;
      #pragma unroll
      for (int j = 0; j < 4; j++){
        int n = bn*128 + wn*64 + j*16 + l16;
        float bv = bb1[n];
        float wv = Wb2f[n];
        #pragma unroll
        for (int r = 0; r < 4; r++)
          rp[r] += fmaxf(acc[i][j][r] + bv, 0.0f) * wv;
      }
      #pragma unroll
      for (int off = 1; off < 16; off <<= 1)
        #pragma unroll
        for (int r = 0; r < 4; r++)
          rp[r] += __shfl_xor(rp[r], off, 64);
      if (l16 == 0){
        #pragma unroll
        for (int r = 0; r < 4; r++){
          int m = bm*128 + wm*64 + i*16 + quad*4 + r;
          __hip_atomic_store(&part[(size_t)(bn*2 + wn)*16384 + m], rp[r],
                             __ATOMIC_RELAXED, __HIP_MEMORY_SCOPE_AGENT);
        }
      }
    }
    asm volatile("s_waitcnt vmcnt(0)" ::: "memory");
    __syncthreads();
    if (tid == 0) atomicAdd(&gemmcnt[seg], 1u);   // device-scope by default
    return;
  }

  // ---------------- softmax role ----------------
  if (seg < 2 && bx >= gemm_base + 512){
    int b = bx - (gemm_base + 512);
    if (tid == 0){
      while (__hip_atomic_load(&gemmcnt[seg], __ATOMIC_RELAXED, __HIP_MEMORY_SCOPE_AGENT) < 512u)
        __builtin_amdgcn_s_sleep(16);
    }
    __syncthreads();
    float* red = (float*)smem;     // 256
    float* cs  = red + 256;        // 256
    int t = tid;
    float raw = 0.0f;
    #pragma unroll
    for (int s = 0; s < 8; s++) raw += part[s*16384 + t*64 + b];   // t-major part
    float lg = (t == 0) ? NEG_INF_F : (raw + bb2[0]);
    lout[b*256 + t] = lg;
    float x = lg + gum[b*256 + t];
    red[t] = x; __syncthreads();
    for (int o = 128; o > 0; o >>= 1){ if (t < o) red[t] = fmaxf(red[t], red[t+o]); __syncthreads(); }
    float mx = red[0]; __syncthreads();
    float e = __expf(x - mx);
    red[t] = e; __syncthreads();
    for (int o = 128; o > 0; o >>= 1){ if (t < o) red[t] += red[t+o]; __syncthreads(); }
    float s = red[0];
    float sb = e / s;
    sbout[b*256 + t] = sb;
    cs[t] = sb; __syncthreads();
    for (int o = 1; o < 256; o <<= 1){
      float v = cs[t];
      if (t >= o) v += cs[t - o];
      __syncthreads();
      cs[t] = v;
      __syncthreads();
    }
    float lc = logf(cs[t] + 1e-17f);
    float acc2 = (seg == 0) ? lc : (logcum[b*256 + t] + lc);
    logcum[b*256 + t] = acc2;
    float mk = __expf(acc2);
    maskf[b*256 + t] = mk;
    maskoutp[b*256 + t] = mk;
    return;
  }

  // ---------------- lstm role (blocks 0..63) — protocol unchanged ----------------
  ubf*   htile = (ubf*)smem;                       // [16][520]
  ubf*   ptile = (ubf*)(smem + 16640);             // [16][136]
  float* ztile = (float*)(smem + 20992);           // [16][132]

  int wv   = tid >> 6;
  int lane = tid & 63, quad = lane >> 4, l16 = lane & 15;
  int bg   = bx >> 4, cg = bx & 15;
  int j0   = cg * 32;

  short8 bfrag[2][16];
  #pragma unroll
  for (int h = 0; h < 2; h++){
    int col = wv*512 + j0 + h*16 + l16;
    #pragma unroll
    for (int kt = 0; kt < 16; kt++){
      short8 t8;
      #pragma unroll
      for (int j = 0; j < 8; j++){
        int k = kt*32 + quad*8 + j;
        t8[j] = (short)f2bf(Whf[(size_t)k * FOURH + col]);
      }
      bfrag[h][kt] = t8;
    }
  }

  float cst0 = 0.0f, cst1 = 0.0f;
  int bl = tid >> 4;
  int up = (tid & 15) * 2;
  int bglob = bg*16 + bl;
  u32* htile32 = (u32*)htile;
  u32* myflag = &flags[(bg*16 + (tid >> 4))*16];

  for (int t = 0; t < 256; ++t){
    {
      int act  = actions[(size_t)bglob * 256 + t];
      int colc = (tid & 15) * 8;
      int gate = colc >> 5, cw = colc & 31;
      uint4 q = *(const uint4*)(Pt + (size_t)act * FOURH + gate*512 + j0 + cw);
      *(uint4*)&ptile[bl*136 + colc] = q;
    }
    if (t > 0){
      unsigned tgt = epoch0 + (unsigned)t;
      while (__hip_atomic_load(myflag, __ATOMIC_RELAXED, __HIP_MEMORY_SCOPE_AGENT) < tgt)
        __builtin_amdgcn_s_sleep(1);
      const u32* src = (const u32*)(hbuf + (size_t)(((t+1)&1)*4 + bg) * 16 * 512);
      u32 tmp[16];
      #pragma unroll
      for (int i = 0; i < 16; i++)
        tmp[i] = __hip_atomic_load(&src[tid + 256*i], __ATOMIC_RELAXED, __HIP_MEMORY_SCOPE_AGENT);
      #pragma unroll
      for (int i = 0; i < 16; i++)
        htile32[i*260 + tid] = tmp[i];
    }
    __syncthreads();   // sync A

    f32x4 a0, a1;
    #pragma unroll
    for (int r = 0; r < 4; r++){ a0[r] = 0.0f; a1[r] = 0.0f; }
    if (t > 0){
      #pragma unroll
      for (int kt = 0; kt < 16; kt++){
        short8 af = *(const short8*)&htile[l16*520 + kt*32 + quad*8];
        a0 = __builtin_amdgcn_mfma_f32_16x16x32_bf16(af, bfrag[0][kt], a0, 0, 0, 0);
        a1 = __builtin_amdgcn_mfma_f32_16x16x32_bf16(af, bfrag[1][kt], a1, 0, 0, 0);
      }
    }
    #pragma unroll
    for (int r = 0; r < 4; r++){
      ztile[(quad*4 + r)*132 + wv*32 + l16]      = a0[r];
      ztile[(quad*4 + r)*132 + wv*32 + 16 + l16] = a1[r];
    }
    __syncthreads();   // sync B

    float m = mask ? mask[(size_t)bglob * 256 + t] : 1.0f;
    f2v ev;
    ubf hp[2];
    #pragma unroll
    for (int p = 0; p < 2; p++){
      int u = up + p;
      float zi = ztile[bl*132 +       u] + bf2f(ptile[bl*136 +       u]);
      float zf = ztile[bl*132 + 32 + u] + bf2f(ptile[bl*136 + 32 + u]);
      float zg = ztile[bl*132 + 64 + u] + bf2f(ptile[bl*136 + 64 + u]);
      float zo = ztile[bl*132 + 96 + u] + bf2f(ptile[bl*136 + 96 + u]);
      float is = sigm(zi), fs = sigm(zf), gt = tanh_fast(zg), os = sigm(zo);
      float cp = p ? cst1 : cst0;
      float cn = fs * cp + is * gt;
      float hn = os * tanh_fast(cn);
      ev[p] = hn;
      float cm = m * cn;
      if (p) cst1 = cm; else cst0 = cm;
      hp[p] = f2bf(m * hn);
    }
    {
      u32 hword = (u32)hp[0] | ((u32)hp[1] << 16);
      u32* dst = (u32*)(hbuf + (size_t)((t&1)*4 + bg) * 16 * 512);
      __hip_atomic_store(&dst[(bl*512 + j0 + up) >> 1], hword,
                         __ATOMIC_RELAXED, __HIP_MEMORY_SCOPE_AGENT);
    }
    __threadfence_block();
    __syncthreads();         // drain: vmcnt(0) -> h-stores at L3
    if (tid == 0)
      __hip_atomic_store(&flags[(bg*16 + cg)*16], epoch0 + (unsigned)t + 1u,
                         __ATOMIC_RELAXED, __HIP_MEMORY_SCOPE_AGENT);
    // enc/encb stores AFTER the announce (off protocol path). encb is sc1
    // (t-major) so same-launch gemm blocks on other XCDs read fresh from L3;
    // it is drained by the NEXT step's drain-barrier (hence the flag t+2 rule).
    *(f2v*)(enc + ((size_t)bglob * 256 + t) * 512 + j0 + up) = ev;
    if (encb){
      u32 ebw = (u32)f2bf(ev[0]) | ((u32)f2bf(ev[1]) << 16);
      __hip_atomic_store((u32*)(encb + ((size_t)t*64 + bglob)*512 + j0 + up), ebw,
                         __ATOMIC_RELAXED, __HIP_MEMORY_SCOPE_AGENT);
    }
  }
  // sentinel: covers encb(t=255) for gemm bm=127 (separate array so it can
  // never alias the next epoch's h-flag targets).
  asm volatile("s_waitcnt vmcnt(0)" ::: "memory");
  if (tid == 0)
    __hip_atomic_store(&sent[(bg*16 + cg)*16], (u32)(seg + 1),
                       __ATOMIC_RELAXED, __HIP_MEMORY_SCOPE_AGENT);
}

// ---------------------------------------------------------------- seg2 tail: one-hot readout gather +
// 512-thread zdec + cooperative broadcast (r18-proven) + folded onehot write.
__global__ __launch_bounds__(512, 1) void zdec2_kernel(
    const float* __restrict__ enc, const int* __restrict__ lengths,
    const float* __restrict__ Wz1, const float* __restrict__ bz1,
    const float* __restrict__ Wz2, const float* __restrict__ bz2,
    const float* __restrict__ epsz,
    const float* __restrict__ Wd1, const float* __restrict__ bd1,
    const float* __restrict__ Wd2, const float* __restrict__ bd2,
    float* __restrict__ lzout, float* __restrict__ szout, float* __restrict__ recseg,
    float* __restrict__ sbout2)
{
  __shared__ float r[512], hz[512], lz[128], sz[64], hd[512];
  __shared__ __align__(16) float row[500];
  int b = blockIdx.x, tid = threadIdx.x;
  int L = lengths[b];
  if (tid < 256) sbout2[b*256 + tid] = (tid == (L - 1)) ? 1.0f : 0.0f;   // folded onehot
  r[tid] = (L >= 2) ? enc[((size_t)b*256 + (L - 2))*512 + tid] : 0.0f;
  __syncthreads();
  {
    float a0 = bz1[tid];
    for (int i = 0; i < 512; i++)
      a0 += r[i] * Wz1[(size_t)i*512 + tid];
    hz[tid] = fmaxf(a0, 0.0f);
  }
  __syncthreads();
  if (tid < 128){
    float a = bz2[tid];
    for (int i = 0; i < 512; i++) a += hz[i] * Wz2[(size_t)i*128 + tid];
    lz[tid] = a;
    lzout[b*128 + tid] = a;
  }
  __syncthreads();
  if (tid < 64){
    float mu = lz[tid], lv = lz[64 + tid];
    float v = mu + __expf(0.5f * lv) * epsz[b*64 + tid];
    sz[tid] = v;
    szout[b*64 + tid] = v;
  }
  __syncthreads();
  {
    float a0 = bd1[tid];
    for (int l = 0; l < 64; l++)
      a0 += sz[l] * Wd1[l*512 + tid];
    hd[tid] = fmaxf(a0, 0.0f);
  }
  __syncthreads();
  if (tid < 500){
    float a0 = bd2[tid];
    for (int h = 0; h < 512; h++)
      a0 += hd[h] * Wd2[(size_t)h*500 + tid];
    row[tid] = a0;
  }
  __syncthreads();
  for (int i = tid; i < 256*125; i += 512){
    int t = i / 125, c = i - t*125;
    *(f4v*)(recseg + (size_t)b*128000 + (size_t)t*500 + c*4) = *(const f4v*)&row[c*4];
  }
}

// ---------------------------------------------------------------- launcher
extern "C" void kernel_launch(void* const* d_in, const int* in_sizes, int n_in,
                              void* d_out, int out_size, void* d_ws, size_t ws_size,
                              hipStream_t stream)
{
  const int*   actions = (const int*)d_in[0];
  const int*   lengths = (const int*)d_in[1];
  const float* gumbel  = (const float*)d_in[2];
  const float* epsz    = (const float*)d_in[3];
  const float* embed   = (const float*)d_in[4];
  const float* Wx      = (const float*)d_in[5];
  const float* Wh      = (const float*)d_in[6];
  const float* b_lstm  = (const float*)d_in[7];
  const float* Wz1     = (const float*)d_in[8];
  const float* bz1     = (const float*)d_in[9];
  const float* Wz2     = (const float*)d_in[10];
  const float* bz2     = (const float*)d_in[11];
  const float* Wb1     = (const float*)d_in[12];
  const float* bb1     = (const float*)d_in[13];
  const float* Wb2     = (const float*)d_in[14];
  const float* bb2     = (const float*)d_in[15];
  const float* Wd1     = (const float*)d_in[16];
  const float* bd1     = (const float*)d_in[17];
  const float* Wd2     = (const float*)d_in[18];
  const float* bd2     = (const float*)d_in[19];
  float* out = (float*)d_out;

  float* r2      = out + (size_t)REC_OFF + 2*(size_t)REC_SEG;
  ubf*   P       = (ubf*)(r2 + SCR_P);
  ubf*   hbuf    = (ubf*)(r2 + SCR_HBUF);
  u32*   flags   = (u32*)(r2 + SCR_FLAGS);
  float* maskf   = r2 + SCR_MASKF;
  float* logcum  = r2 + SCR_LOGCUM;
  float* partf   = r2 + SCR_PART;
  u32*   sent    = (u32*)(r2 + SCR_SENT);
  u32*   cnt     = (u32*)(r2 + SCR_CNT);
  ubf*   encb    = (ubf*)(r2 + SCR_ENCB);

  hipLaunchKernelGGL(init_kernel, dim3(1), dim3(256), 0, stream, flags, sent, cnt);

  hipLaunchKernelGGL(gemm_kernel, dim3(16, 4), dim3(256), 0, stream,
                     (const void*)embed, 1, Wx, b_lstm, P,
                     (const float*)nullptr, (float*)nullptr,
                     512, 2048, 512, 0, 499);

  for (int seg = 0; seg < 3; ++seg){
    int prev = (seg > 0) ? (seg - 1) : 0;
    int grid = (seg == 0) ? 640 : (seg == 1) ? 704 : 128;
    hipLaunchKernelGGL(mega_kernel, dim3(grid), dim3(256), 0, stream,
                       seg,
                       P, actions, Wh,
                       (seg == 0) ? (const float*)nullptr : maskf,
                       out + (size_t)seg * ENC_SEG,
                       (seg < 2) ? encb : (ubf*)nullptr,
                       hbuf, flags, sent,
                       Wb1, bb1, Wb2, partf, cnt,
                       bb2, gumbel + (size_t)seg * 16384,
                       out + LOGB_OFF + (size_t)seg * 16384,
                       out + SAMB_OFF + (size_t)seg * 16384,
                       logcum, maskf, out + MASK_OFF + (size_t)seg * 16384,
                       out + (size_t)prev * ENC_SEG,
                       out + SAMB_OFF + (size_t)prev * 16384,
                       epsz + (size_t)prev * 4096,
                       Wz1, bz1, Wz2, bz2, Wd1, bd1, Wd2, bd2,
                       out + LOGZ_OFF + (size_t)prev * 8192,
                       out + SAMZ_OFF + (size_t)prev * 4096,
                       out + REC_OFF + (size_t)prev * REC_SEG);
  }
  hipLaunchKernelGGL(zdec2_kernel, dim3(64), dim3(512), 0, stream,
                     out + (size_t)2 * ENC_SEG, lengths,
                     Wz1, bz1, Wz2, bz2,
                     epsz + (size_t)2 * 4096,
                     Wd1, bd1, Wd2, bd2,
                     out + LOGZ_OFF + (size_t)2 * 8192,
                     out + SAMZ_OFF + (size_t)2 * 4096,
                     out + REC_OFF + (size_t)2 * REC_SEG,
                     out + SAMB_OFF + (size_t)2 * 16384);
  (void)in_sizes; (void)n_in; (void)out_size; (void)d_ws; (void)ws_size;
}